// Round 1
// baseline (127.520 us; speedup 1.0000x reference)
//
#include <hip/hip_runtime.h>

// BottleneckAdapter: out = residual + Wup·( swish(Wl1·n+bl1) * (Wl2·n+bl2) ),
// n = LN( (Wdown·Wproj)·x ).  W_comb = Wdown@Wproj precomputed per-launch.
//
// Dims: B=16 S=2048 C=768 Q=1024 D=64 -> ROWS=32768.

#define ROWS 32768
#define CDIM 768
#define QDIM 1024
#define DDIM 64

typedef __attribute__((ext_vector_type(8))) short bf16x8;
typedef __attribute__((ext_vector_type(4))) float f32x4;

__device__ __forceinline__ ushort f2bf(float f) {
  union { float f; unsigned u; } v; v.f = f;
  unsigned r = v.u + 0x7fffu + ((v.u >> 16) & 1u);   // RNE
  return (ushort)(r >> 16);
}

// ---- K1: partial W_comb[d][c] = sum_q Wdown[d][q]*Wproj[q][c], split in 8 q-chunks.
// part[qc][c][d]  (8 x 768 x 64 f32)
__global__ void k_wcomb(const float* __restrict__ Wproj, const float* __restrict__ Wdown,
                        float* __restrict__ part) {
  int bid = blockIdx.x;                 // 768 blocks = 12 cb * 8 db * 8 qc
  int cb = bid % 12, db = (bid / 12) % 8, qc = bid / 96;
  int l = threadIdx.x;                  // 64
  int c = cb * 64 + l;
  float acc[8];
  #pragma unroll
  for (int i = 0; i < 8; ++i) acc[i] = 0.f;
  int q0 = qc * 128;
  for (int q = q0; q < q0 + 128; ++q) {
    float xp = Wproj[q * CDIM + c];     // coalesced across lanes
    #pragma unroll
    for (int i = 0; i < 8; ++i)
      acc[i] = fmaf(Wdown[(db * 8 + i) * QDIM + q], xp, acc[i]);  // uniform, L2
  }
  #pragma unroll
  for (int i = 0; i < 8; ++i)
    part[((size_t)qc * CDIM + c) * 64 + db * 8 + i] = acc[i];
}

// ---- K2: sum partials + arrange all weights into MFMA B-fragment order (bf16).
// Fragment layout convention (k-permutation trick: A and B share it, so the true
// HW k-map cancels): element (lane l, j) of tile (ks,nf) = B[32*ks + 8*(l>>4)+j][16*nf+(l&15)]
__global__ void k_arrange(const float* __restrict__ part, const float* __restrict__ Wup,
                          const float* __restrict__ Wl1, const float* __restrict__ Wl2,
                          ushort* __restrict__ wcf, ushort* __restrict__ wupf,
                          ushort* __restrict__ wl1f, ushort* __restrict__ wl2f) {
  int idx = blockIdx.x * 256 + threadIdx.x;      // 480*256 = 122880 exactly
  if (idx < 49152) {                             // wcf: flat = ((ks*4+nf)*64+l)*8+j, ks<24
    int i0 = idx;
    int j = i0 & 7, l = (i0 >> 3) & 63, t = i0 >> 9;
    int g = l >> 4, r16 = l & 15;
    int nf = t & 3, ks = t >> 2;
    int k = 32 * ks + 8 * g + j, n = 16 * nf + r16;   // k=c-index, n=d-index
    float s = 0.f;
    #pragma unroll
    for (int qc = 0; qc < 8; ++qc) s += part[((size_t)qc * CDIM + k) * 64 + n];
    wcf[i0] = f2bf(s);
  } else if (idx < 49152 + 65536) {              // wupf: flat = ((nf*2+ks)*64+l)*8+j, nf<64
    int i2 = idx - 49152;
    int j = i2 & 7, l = (i2 >> 3) & 63, t = i2 >> 9;
    int g = l >> 4, r16 = l & 15;
    int ks = t & 1, nf = t >> 1;
    int k = 32 * ks + 8 * g + j, n = 16 * nf + r16;   // up[n] = sum_k a[k]*Wup[n][k]
    wupf[i2] = f2bf(Wup[n * 64 + k]);
  } else if (idx < 49152 + 65536 + 4096) {       // wl1f: flat = ((ks*4+nf)*64+l)*8+j
    int i3 = idx - (49152 + 65536);
    int j = i3 & 7, l = (i3 >> 3) & 63, t = i3 >> 9;
    int g = l >> 4, r16 = l & 15;
    int nf = t & 3, ks = t >> 2;
    int k = 32 * ks + 8 * g + j, e = 16 * nf + r16;   // o1[e] = sum_k n[k]*Wl1[e][k]
    wl1f[i3] = f2bf(Wl1[e * 64 + k]);
  } else {                                       // wl2f
    int i4 = idx - (49152 + 65536 + 4096);
    int j = i4 & 7, l = (i4 >> 3) & 63, t = i4 >> 9;
    int g = l >> 4, r16 = l & 15;
    int nf = t & 3, ks = t >> 2;
    int k = 32 * ks + 8 * g + j, e = 16 * nf + r16;
    wl2f[i4] = f2bf(Wl2[e * 64 + k]);
  }
}

// ---- K3: fused main kernel. 16 rows per WG, 4 waves.
__global__ __launch_bounds__(256, 4)
void k_fused(const float* __restrict__ xg, const float* __restrict__ resg,
             const float* __restrict__ gamma, const float* __restrict__ beta,
             const float* __restrict__ bl1, const float* __restrict__ bl2,
             const ushort* __restrict__ wcf, const ushort* __restrict__ wupf,
             const ushort* __restrict__ wl1f, const ushort* __restrict__ wl2f,
             float* __restrict__ outg) {
  __shared__ ushort x_lds[16][776];   // bf16 x-tile, row pad 768->776 (bank spread)
  __shared__ float  d_lds[16][68];    // fp32 down-proj tile
  __shared__ ushort n_lds[16][72];    // bf16 normalized
  __shared__ ushort a_lds[16][72];    // bf16 activated

  const int tid = threadIdx.x;
  const int w = tid >> 6, l = tid & 63, g = l >> 4, r16 = l & 15;
  const int row0 = blockIdx.x * 16;

  // Phase A: stage x (16x768 f32) -> LDS bf16, float4-vectorized, coalesced.
  #pragma unroll
  for (int i = 0; i < 12; ++i) {
    int f4 = i * 256 + tid;                    // 0..3071
    int r = f4 / 192;                          // 768/4=192 float4 per row
    int c4 = (f4 - r * 192) * 4;
    const float4 v = *reinterpret_cast<const float4*>(xg + (size_t)(row0 + r) * CDIM + c4);
    ushort4 b;
    b.x = f2bf(v.x); b.y = f2bf(v.y); b.z = f2bf(v.z); b.w = f2bf(v.w);
    *reinterpret_cast<ushort4*>(&x_lds[r][c4]) = b;
  }
  __syncthreads();

  // Phase B: d(16x64) = x(16x768) * Wcomb^T. Wave w owns n-frag w (cols 16w..16w+15).
  f32x4 dacc = {0.f, 0.f, 0.f, 0.f};
  #pragma unroll 4
  for (int ks = 0; ks < 24; ++ks) {
    bf16x8 a = *reinterpret_cast<const bf16x8*>(&x_lds[r16][ks * 32 + 8 * g]);
    bf16x8 b = *reinterpret_cast<const bf16x8*>(wcf + ((size_t)(ks * 4 + w) * 64 + l) * 8);
    dacc = __builtin_amdgcn_mfma_f32_16x16x32_bf16(a, b, dacc, 0, 0, 0);
  }
  #pragma unroll
  for (int rg = 0; rg < 4; ++rg) d_lds[4 * g + rg][16 * w + r16] = dacc[rg];
  __syncthreads();

  // Phase C: LayerNorm over D=64. Wave w rows 4w..4w+3; 16 lanes x 4 cols per row.
  {
    int row = 4 * w + g;
    f32x4 v = *reinterpret_cast<const f32x4*>(&d_lds[row][4 * r16]);
    float s  = v[0] + v[1] + v[2] + v[3];
    float sq = v[0]*v[0] + v[1]*v[1] + v[2]*v[2] + v[3]*v[3];
    #pragma unroll
    for (int m = 1; m < 16; m <<= 1) {
      s  += __shfl_xor(s, m, 64);
      sq += __shfl_xor(sq, m, 64);
    }
    float mu  = s * (1.f / 64.f);
    float var = sq * (1.f / 64.f) - mu * mu;
    float rs  = rsqrtf(var + 1e-5f);
    const float4 gm = *reinterpret_cast<const float4*>(gamma + 4 * r16);
    const float4 bt = *reinterpret_cast<const float4*>(beta  + 4 * r16);
    ushort4 nb;
    nb.x = f2bf((v[0] - mu) * rs * gm.x + bt.x);
    nb.y = f2bf((v[1] - mu) * rs * gm.y + bt.y);
    nb.z = f2bf((v[2] - mu) * rs * gm.z + bt.z);
    nb.w = f2bf((v[3] - mu) * rs * gm.w + bt.w);
    *reinterpret_cast<ushort4*>(&n_lds[row][4 * r16]) = nb;
  }
  __syncthreads();

  // Phase D: o1/o2 (16x64, K=64) + bias + swish*gate -> a_lds. Wave w -> n-frag w.
  {
    bf16x8 a0 = *reinterpret_cast<const bf16x8*>(&n_lds[r16][8 * g]);
    bf16x8 a1 = *reinterpret_cast<const bf16x8*>(&n_lds[r16][32 + 8 * g]);
    bf16x8 b10 = *reinterpret_cast<const bf16x8*>(wl1f + ((size_t)(0 * 4 + w) * 64 + l) * 8);
    bf16x8 b11 = *reinterpret_cast<const bf16x8*>(wl1f + ((size_t)(1 * 4 + w) * 64 + l) * 8);
    bf16x8 b20 = *reinterpret_cast<const bf16x8*>(wl2f + ((size_t)(0 * 4 + w) * 64 + l) * 8);
    bf16x8 b21 = *reinterpret_cast<const bf16x8*>(wl2f + ((size_t)(1 * 4 + w) * 64 + l) * 8);
    f32x4 z = {0.f, 0.f, 0.f, 0.f};
    f32x4 acc1 = __builtin_amdgcn_mfma_f32_16x16x32_bf16(a0, b10, z, 0, 0, 0);
    acc1 = __builtin_amdgcn_mfma_f32_16x16x32_bf16(a1, b11, acc1, 0, 0, 0);
    f32x4 acc2 = __builtin_amdgcn_mfma_f32_16x16x32_bf16(a0, b20, z, 0, 0, 0);
    acc2 = __builtin_amdgcn_mfma_f32_16x16x32_bf16(a1, b21, acc2, 0, 0, 0);
    float bv1 = bl1[16 * w + r16];
    float bv2 = bl2[16 * w + r16];
    #pragma unroll
    for (int rg = 0; rg < 4; ++rg) {
      float o1 = acc1[rg] + bv1;
      float o2 = acc2[rg] + bv2;
      float sw = o1 / (1.f + __expf(-o1));       // o1*sigmoid(o1)
      a_lds[4 * g + rg][16 * w + r16] = f2bf(sw * o2);
    }
  }
  __syncthreads();

  // Phase E: up(16x1024, K=64) + residual add. Wave w -> cols 256w..256w+255.
  {
    bf16x8 a0 = *reinterpret_cast<const bf16x8*>(&a_lds[r16][8 * g]);
    bf16x8 a1 = *reinterpret_cast<const bf16x8*>(&a_lds[r16][32 + 8 * g]);
    #pragma unroll
    for (int cc = 0; cc < 4; ++cc) {
      f32x4 acc[4];
      #pragma unroll
      for (int i = 0; i < 4; ++i) {
        int nf = 16 * w + 4 * cc + i;
        bf16x8 b0 = *reinterpret_cast<const bf16x8*>(wupf + ((size_t)(nf * 2 + 0) * 64 + l) * 8);
        bf16x8 b1 = *reinterpret_cast<const bf16x8*>(wupf + ((size_t)(nf * 2 + 1) * 64 + l) * 8);
        f32x4 t = {0.f, 0.f, 0.f, 0.f};
        t = __builtin_amdgcn_mfma_f32_16x16x32_bf16(a0, b0, t, 0, 0, 0);
        acc[i] = __builtin_amdgcn_mfma_f32_16x16x32_bf16(a1, b1, t, 0, 0, 0);
      }
      #pragma unroll
      for (int i = 0; i < 4; ++i) {
        int col = 16 * (16 * w + 4 * cc + i) + r16;
        #pragma unroll
        for (int rg = 0; rg < 4; ++rg) {
          size_t off = (size_t)(row0 + 4 * g + rg) * QDIM + col;
          outg[off] = resg[off] + acc[i][rg];
        }
      }
    }
  }
}

extern "C" void kernel_launch(void* const* d_in, const int* in_sizes, int n_in,
                              void* d_out, int out_size, void* d_ws, size_t ws_size,
                              hipStream_t stream) {
  (void)in_sizes; (void)n_in; (void)out_size; (void)ws_size;
  const float* x     = (const float*)d_in[0];
  const float* resid = (const float*)d_in[1];
  const float* Wproj = (const float*)d_in[2];
  const float* Wdown = (const float*)d_in[3];
  const float* gamma = (const float*)d_in[4];
  const float* beta  = (const float*)d_in[5];
  const float* Wl1   = (const float*)d_in[6];
  const float* bl1   = (const float*)d_in[7];
  const float* Wl2   = (const float*)d_in[8];
  const float* bl2   = (const float*)d_in[9];
  const float* Wup   = (const float*)d_in[10];
  float* out = (float*)d_out;

  char* ws = (char*)d_ws;
  float*  part = (float*)(ws);                   // 8*768*64*4 = 1,572,864 B
  ushort* wcf  = (ushort*)(ws + 1572864);        // 49152*2 =  98,304 B
  ushort* wupf = (ushort*)(ws + 1671168);        // 65536*2 = 131,072 B
  ushort* wl1f = (ushort*)(ws + 1802240);        //  4096*2 =   8,192 B
  ushort* wl2f = (ushort*)(ws + 1810432);        //  4096*2 =   8,192 B  (end 1,818,624)

  k_wcomb  <<<768, 64, 0, stream>>>(Wproj, Wdown, part);
  k_arrange<<<480, 256, 0, stream>>>(part, Wup, Wl1, Wl2, wcf, wupf, wl1f, wl2f);
  k_fused  <<<2048, 256, 0, stream>>>(x, resid, gamma, beta, bl1, bl2,
                                      wcf, wupf, wl1f, wl2f, out);
}